// Round 8
// baseline (1544.499 us; speedup 1.0000x reference)
//
#include <hip/hip_runtime.h>
#include <hip/hip_bf16.h>
#include <stdint.h>
#include <math.h>

// ============================================================================
// R8 = R7 resubmitted (R7 bench was an infra failure: "container failed
// twice"; kernel never ran). R6's occupancy attack, de-spilled. R6 counters:
// occupancy 83% (worked) but WRITE_SIZE 4MB->146MB = scratch spills
// (launch_bounds(512,8) forced a 32-reg arch budget; stage-4 acc[4][4] +
// tier-2 doubles spilled) -> 1477us. Fix: launch_bounds(512,4) (R5-proven:
// compiler lands on 64 VGPR, no spill; <=64 VGPR + 38.9KB LDS -> 4 blocks/CU
// at runtime) and lighter stage 4 (400 threads, acc[2][4], peak live ~26
// regs). Everything else byte-identical to R6 (passed, absmax 9.77e-4).
// ============================================================================

typedef _Float16 f16x8 __attribute__((ext_vector_type(8)));
typedef float    f32x4 __attribute__((ext_vector_type(4)));

#define NROWS 16
#define CERT_E  5e-5f
#define CERT_E2 2e-5

// ws plane offsets (bytes). Planes are row-major [N][K] fp16.
#define OW2H 0          // W2  [256][128]
#define OW2L 65536
#define OW3H 131072     // W3  [256][256]  (rows 200..255 zero)
#define OW3L 262144
#define WS_NEED 393216

#define SA1 132
#define SA2 260
#define SA3 204
#define SP  108

__device__ __forceinline__ void split16(float v, _Float16& hi, _Float16& lo) {
  hi = (_Float16)v;
  lo = (_Float16)((v - (float)hi) * 2048.f);
}

// fp32 4x4 tile body (fallback kernel; rows rq+8r).
template<int K>
__device__ __forceinline__ void tile_acc(const float* __restrict__ hbase, int hstride,
                                         const float* __restrict__ W,
                                         const float* __restrict__ bias,
                                         int rq, int cq, float acc[4][4]) {
  float4 bv = *(const float4*)(bias + cq * 4);
#pragma unroll
  for (int r = 0; r < 4; ++r) {
    acc[r][0] = bv.x; acc[r][1] = bv.y; acc[r][2] = bv.z; acc[r][3] = bv.w;
  }
  const float* h0 = hbase + rq * hstride;
#pragma unroll 2
  for (int k = 0; k < K; k += 4) {
    float4 h4[4];
#pragma unroll
    for (int r = 0; r < 4; ++r) h4[r] = *(const float4*)(h0 + (r * 8) * hstride + k);
#pragma unroll
    for (int c = 0; c < 4; ++c) {
      float4 w4 = *(const float4*)(W + (size_t)(cq * 4 + c) * K + k);
#pragma unroll
      for (int r = 0; r < 4; ++r) {
        acc[r][c] = fmaf(h4[r].x, w4.x, acc[r][c]);
        acc[r][c] = fmaf(h4[r].y, w4.y, acc[r][c]);
        acc[r][c] = fmaf(h4[r].z, w4.z, acc[r][c]);
        acc[r][c] = fmaf(h4[r].w, w4.w, acc[r][c]);
      }
    }
  }
}

// fp64-accum pi dot over LDS fp32 h3 row (tier-2 cert).
__device__ __forceinline__ double pidot64(const float* __restrict__ hr,
                                          const float* __restrict__ Wpi,
                                          const float* __restrict__ bpi, int n) {
  double a = (double)bpi[n];
  const float* wq = Wpi + (size_t)n * 200;
  for (int k = 0; k < 200; k += 4) {
    float4 w4 = *(const float4*)(wq + k);
    a = fma((double)hr[k],     (double)w4.x, a);
    a = fma((double)hr[k + 1], (double)w4.y, a);
    a = fma((double)hr[k + 2], (double)w4.z, a);
    a = fma((double)hr[k + 3], (double)w4.w, a);
  }
  return a;
}

// ---------------------------------------------------------------------------
// Prep: split W2/W3 into fp16 hi / scaled-lo planes in workspace.
// ---------------------------------------------------------------------------
extern "C" __global__ void mdn_prep(const float* __restrict__ W2,
                                    const float* __restrict__ W3,
                                    unsigned char* __restrict__ ws) {
  const int stride = gridDim.x * blockDim.x;
  const int gid = blockIdx.x * blockDim.x + threadIdx.x;

  _Float16* w2h = (_Float16*)(ws + OW2H);
  _Float16* w2l = (_Float16*)(ws + OW2L);
  for (int e = gid; e < 256 * 128; e += stride) {
    _Float16 h, l; split16(W2[e], h, l);
    w2h[e] = h; w2l[e] = l;
  }

  _Float16* w3h = (_Float16*)(ws + OW3H);
  _Float16* w3l = (_Float16*)(ws + OW3L);
  for (int e = gid; e < 256 * 256; e += stride) {
    int n = e >> 8;
    float x = (n < 200) ? W3[e] : 0.f;
    _Float16 h, l; split16(x, h, l);
    w3h[e] = h; w3l[e] = l;
  }
}

// ---------------------------------------------------------------------------
// Main kernel. 512 threads, 16 rows/block, ~38.5KB LDS.
// A-fragment layout per plane (NKT k-tiles):
//   byte = (kt*64 + ((k>>3)&3)*16 + row)*16 + (k&7)*2   (row 0..15)
// ---------------------------------------------------------------------------
extern "C" __global__ void __launch_bounds__(512, 4)
fused_mdn_mfma(const float* __restrict__ x0,  const float* __restrict__ rnd,
               const float* __restrict__ gmb,
               const float* __restrict__ W1,  const float* __restrict__ b1,
               const float* __restrict__ W2,  const float* __restrict__ b2,
               const float* __restrict__ W3,  const float* __restrict__ b3,
               const float* __restrict__ Wmu, const float* __restrict__ bmu,
               const float* __restrict__ Wsg, const float* __restrict__ bsg,
               const float* __restrict__ Wpi, const float* __restrict__ bpi,
               const unsigned char* __restrict__ ws,
               float* __restrict__ out)
{
  // smem map:
  //   [0,16384)      regA: h2 frags (hi 8K @0 | lo 8K @8192).
  //                  After stage 3: pv (6912) @0; part (6400) @8192;
  //                  sprt (512) @8192; repair doubles (5536) @8192.
  //   [16384,24576)  regC: h1 frags (hi 4K | lo 4K); after stage 4: ps @16384
  //   [24576,37632)  h3f: fp32 h3 [16][204]
  __shared__ __attribute__((aligned(16))) unsigned char smem[37632];
  __shared__ int   idxsh[64];
  __shared__ float mush[64];
  __shared__ float sigsh[64];
  __shared__ unsigned char fsite[64];
  __shared__ int   flagrows[16];
  __shared__ int   nflag;
  __shared__ int   ridx[4];

  unsigned char* regA = smem;
  unsigned char* regC = smem + 16384;
  float* h3f  = (float*)(smem + 24576);
  float* pv   = (float*)smem;
  float* ps   = (float*)(smem + 16384);
  float* part = (float*)(smem + 8192);    // stage-4 partials [8][200]
  float* sprt = (float*)(smem + 8192);    // stage-5 partials [128]

  const int tid  = threadIdx.x;
  const int lane = tid & 63;
  const int w    = tid >> 6;     // wave 0..7
  const int ln   = lane & 15;    // non-k dim selector
  const int ks   = lane >> 4;    // k sub-block 0..3
  const int r0   = blockIdx.x * NROWS;

  if (tid == 0) nflag = 0;

  // ---- Stage 1: h1 = relu(x0 @ W1^T + b1), K=3 -> h1frag in regC ----
  if (tid < 256) {
    int row = tid & 15, cg = tid >> 4;       // cg 0..15
    const float* xr = x0 + (size_t)(r0 + row) * 3;
    float xv0 = xr[0], xv1 = xr[1], xv2 = xr[2];
    int c0 = cg * 8;
    f16x8 vh, vl;
#pragma unroll
    for (int c = 0; c < 8; ++c) {
      int col = c0 + c;
      float a = b1[col];
      a = fmaf(xv0, W1[col * 3 + 0], a);
      a = fmaf(xv1, W1[col * 3 + 1], a);
      a = fmaf(xv2, W1[col * 3 + 2], a);
      a = fmaxf(a, 0.f);
      _Float16 h, l; split16(a, h, l);
      vh[c] = h; vl[c] = l;
    }
    int kt = c0 >> 5, sub = (c0 >> 3) & 3;
    int off = (kt * 64 + sub * 16 + row) * 16;
    *(f16x8*)(regC + off)        = vh;
    *(f16x8*)(regC + 4096 + off) = vl;
  }
  __syncthreads();

  // ---- Stage 2: h2 = relu(h1 @ W2^T + b2)  M=16 N=256 K=128 (NKT=4) ----
  {
    f32x4 a1[2], a2[2];                       // [cbi]
#pragma unroll
    for (int i = 0; i < 2; ++i) {
      a1[i] = (f32x4){0.f, 0.f, 0.f, 0.f};
      a2[i] = (f32x4){0.f, 0.f, 0.f, 0.f};
    }
    const unsigned char* bp0 = ws + OW2H + (size_t)((w       * 16 + ln) * 256) + ks * 16;
    const unsigned char* bp1 = ws + OW2H + (size_t)(((w + 8) * 16 + ln) * 256) + ks * 16;
#pragma unroll
    for (int kt = 0; kt < 4; ++kt) {
      int ao = (kt * 64 + lane) * 16;
      f16x8 Ah = *(const f16x8*)(regC + ao);
      f16x8 Al = *(const f16x8*)(regC + 4096 + ao);
      {
        f16x8 Bh = *(const f16x8*)(bp0 + kt * 64);
        f16x8 Bl = *(const f16x8*)(bp0 + 65536 + kt * 64);
        a1[0] = __builtin_amdgcn_mfma_f32_16x16x32_f16(Ah, Bh, a1[0], 0, 0, 0);
        a2[0] = __builtin_amdgcn_mfma_f32_16x16x32_f16(Ah, Bl, a2[0], 0, 0, 0);
        a2[0] = __builtin_amdgcn_mfma_f32_16x16x32_f16(Al, Bh, a2[0], 0, 0, 0);
      }
      {
        f16x8 Bh = *(const f16x8*)(bp1 + kt * 64);
        f16x8 Bl = *(const f16x8*)(bp1 + 65536 + kt * 64);
        a1[1] = __builtin_amdgcn_mfma_f32_16x16x32_f16(Ah, Bh, a1[1], 0, 0, 0);
        a2[1] = __builtin_amdgcn_mfma_f32_16x16x32_f16(Ah, Bl, a2[1], 0, 0, 0);
        a2[1] = __builtin_amdgcn_mfma_f32_16x16x32_f16(Al, Bh, a2[1], 0, 0, 0);
      }
    }
#pragma unroll
    for (int cbi = 0; cbi < 2; ++cbi) {
      int col = (w + cbi * 8) * 16 + ln;                  // 0..255
      float bb = b2[col];
      int kt2 = col >> 5, sub2 = (col >> 3) & 3, j2 = col & 7;
#pragma unroll
      for (int r = 0; r < 4; ++r) {
        float v = a1[cbi][r] + a2[cbi][r] * (1.f / 2048.f) + bb;
        v = fmaxf(v, 0.f);
        _Float16 h, l; split16(v, h, l);
        int off = (kt2 * 64 + sub2 * 16 + (ks * 4 + r)) * 16 + j2 * 2;
        *(_Float16*)(regA + off)        = h;
        *(_Float16*)(regA + 8192 + off) = l;
      }
    }
  }
  __syncthreads();

  // ---- Stage 3: h3 = relu(h2 @ W3^T + b3) -> PLAIN FP32 h3f[16][204] ----
  {
    f32x4 a1[2], a2[2];
#pragma unroll
    for (int i = 0; i < 2; ++i) {
      a1[i] = (f32x4){0.f, 0.f, 0.f, 0.f};
      a2[i] = (f32x4){0.f, 0.f, 0.f, 0.f};
    }
    const unsigned char* bp0 = ws + OW3H + (size_t)((w       * 16 + ln) * 512) + ks * 16;
    const unsigned char* bp1 = ws + OW3H + (size_t)(((w + 8) * 16 + ln) * 512) + ks * 16;
#pragma unroll
    for (int kt = 0; kt < 8; ++kt) {
      int ao = (kt * 64 + lane) * 16;
      f16x8 Ah = *(const f16x8*)(regA + ao);
      f16x8 Al = *(const f16x8*)(regA + 8192 + ao);
      {
        f16x8 Bh = *(const f16x8*)(bp0 + kt * 64);
        f16x8 Bl = *(const f16x8*)(bp0 + 131072 + kt * 64);
        a1[0] = __builtin_amdgcn_mfma_f32_16x16x32_f16(Ah, Bh, a1[0], 0, 0, 0);
        a2[0] = __builtin_amdgcn_mfma_f32_16x16x32_f16(Ah, Bl, a2[0], 0, 0, 0);
        a2[0] = __builtin_amdgcn_mfma_f32_16x16x32_f16(Al, Bh, a2[0], 0, 0, 0);
      }
      {
        f16x8 Bh = *(const f16x8*)(bp1 + kt * 64);
        f16x8 Bl = *(const f16x8*)(bp1 + 131072 + kt * 64);
        a1[1] = __builtin_amdgcn_mfma_f32_16x16x32_f16(Ah, Bh, a1[1], 0, 0, 0);
        a2[1] = __builtin_amdgcn_mfma_f32_16x16x32_f16(Ah, Bl, a2[1], 0, 0, 0);
        a2[1] = __builtin_amdgcn_mfma_f32_16x16x32_f16(Al, Bh, a2[1], 0, 0, 0);
      }
    }
#pragma unroll
    for (int cbi = 0; cbi < 2; ++cbi) {
      int col = (w + cbi * 8) * 16 + ln;                  // 0..255; keep <200
      if (col < 200) {
        float bb = b3[col];
#pragma unroll
        for (int r = 0; r < 4; ++r) {
          float v = a1[cbi][r] + a2[cbi][r] * (1.f / 2048.f) + bb;
          h3f[(ks * 4 + r) * SA3 + col] = fmaxf(v, 0.f);
        }
      }
    }
  }
  __syncthreads();

  // ---- Stage 4: pi head M=16 N=100 K=200, 2-way K-split over 400 threads,
  //      acc[2][4] per thread (rows rq, rq+8) -> low register pressure ----
  {
    float acc[2][4];
    if (tid < 400) {
      const int t  = (tid < 200) ? tid : tid - 200;
      const int kh = (tid >= 200) ? 1 : 0;
      const int rq = t & 7, cq = t >> 3;      // rq 0..7, cq 0..24
      if (kh == 0) {
        float4 bv = *(const float4*)(bpi + cq * 4);
#pragma unroll
        for (int r = 0; r < 2; ++r) {
          acc[r][0] = bv.x; acc[r][1] = bv.y; acc[r][2] = bv.z; acc[r][3] = bv.w;
        }
      } else {
#pragma unroll
        for (int r = 0; r < 2; ++r)
          acc[r][0] = acc[r][1] = acc[r][2] = acc[r][3] = 0.f;
      }
      const float* h0 = h3f + kh * 100 + rq * SA3;
      const float* Wb = Wpi + kh * 100;
#pragma unroll 2
      for (int k = 0; k < 100; k += 4) {
        float4 ha = *(const float4*)(h0 + k);
        float4 hb = *(const float4*)(h0 + 8 * SA3 + k);
#pragma unroll
        for (int c = 0; c < 4; ++c) {
          float4 w4 = *(const float4*)(Wb + (size_t)(cq * 4 + c) * 200 + k);
          acc[0][c] = fmaf(ha.x, w4.x, acc[0][c]);
          acc[0][c] = fmaf(ha.y, w4.y, acc[0][c]);
          acc[0][c] = fmaf(ha.z, w4.z, acc[0][c]);
          acc[0][c] = fmaf(ha.w, w4.w, acc[0][c]);
          acc[1][c] = fmaf(hb.x, w4.x, acc[1][c]);
          acc[1][c] = fmaf(hb.y, w4.y, acc[1][c]);
          acc[1][c] = fmaf(hb.z, w4.z, acc[1][c]);
          acc[1][c] = fmaf(hb.w, w4.w, acc[1][c]);
        }
      }
      if (kh) {
#pragma unroll
        for (int r = 0; r < 2; ++r)
#pragma unroll
          for (int c = 0; c < 4; ++c)
            part[(r * 4 + c) * 200 + t] = acc[r][c];
      }
    }
    __syncthreads();
    if (tid < 200) {
      const int rq = tid & 7, cq = tid >> 3;
#pragma unroll
      for (int r = 0; r < 2; ++r)
#pragma unroll
        for (int c = 0; c < 4; ++c)
          acc[r][c] += part[(r * 4 + c) * 200 + tid];
#pragma unroll
      for (int r = 0; r < 2; ++r) {
        int row = rq + 8 * r;
        float4 g4 = *(const float4*)(gmb + (size_t)(r0 + row) * 100 + cq * 4);
        float4 pq, sq;
        pq.x = fabsf(acc[r][0]) + 1e-12f; sq.x = logf(pq.x) + g4.x;
        pq.y = fabsf(acc[r][1]) + 1e-12f; sq.y = logf(pq.y) + g4.y;
        pq.z = fabsf(acc[r][2]) + 1e-12f; sq.z = logf(pq.z) + g4.z;
        pq.w = fabsf(acc[r][3]) + 1e-12f; sq.w = logf(pq.w) + g4.w;
        *(float4*)(pv + row * SP + cq * 4) = pq;
        *(float4*)(ps + row * SP + cq * 4) = sq;
      }
    }
  }
  __syncthreads();

  // ---- Stage 4.5: argmax + tier-1 interval certification per (row,d) ----
  if (tid < 64) {
    int rw = tid >> 2, d = tid & 3;
    const float* pr = ps + rw * SP + d;
    const float* qr = pv + rw * SP + d;
    float s1 = pr[0]; int g1 = 0;
#pragma unroll
    for (int g = 1; g < 25; ++g) {
      float s = pr[g * 4];
      if (s > s1) { s1 = s; g1 = g; }     // strict > == first-occurrence argmax
    }
    unsigned char viol = 0;
    float p1 = qr[g1 * 4];
    if (p1 <= 2.f * CERT_E) {
      viol = 1;
    } else {
      float thr = s1 + logf(1.f - CERT_E / p1);
#pragma unroll
      for (int g = 0; g < 25; ++g) {
        if (g != g1) {
          float shi = pr[g * 4] + logf(1.f + CERT_E / qr[g * 4]);
          if (shi >= thr) viol = 1;
        }
      }
    }
    idxsh[tid] = g1;
    fsite[tid] = viol;
  }
  __syncthreads();

  // ---- Stage 4.6: tier-2 fp64-accum re-cert of flagged sites ----
  if (tid < 64 && fsite[tid]) {
    int rw = tid >> 2, d = tid & 3;
    const float* pr = ps + rw * SP + d;
    const float* qr = pv + rw * SP + d;
    const float* hr = h3f + rw * SA3;
    int g1 = idxsh[tid];
    float p1 = qr[g1 * 4];
    if (p1 > 2.f * CERT_E) {
      float s1 = pr[g1 * 4];
      float thr = s1 + logf(1.f - CERT_E / p1);
      unsigned mask = 1u << g1;
#pragma unroll
      for (int g = 0; g < 25; ++g) {
        if (g != g1) {
          float shi = pr[g * 4] + logf(1.f + CERT_E / qr[g * 4]);
          if (shi >= thr) mask |= (1u << g);
        }
      }
      double sbest = 0.0, pbest = 0.0; int gbest = -1;
      for (int g = 0; g < 25; ++g) {
        if (mask & (1u << g)) {
          int n = g * 4 + d;
          double a = pidot64(hr, Wpi, bpi, n);
          double p64 = fabs(a) + 1e-12;
          double s64 = log(p64) + (double)gmb[(size_t)(r0 + rw) * 100 + n];
          if (gbest < 0 || s64 > sbest) { sbest = s64; pbest = p64; gbest = g; }
        }
      }
      bool ok = (pbest > 2.0 * CERT_E2);
      if (ok) {
        double thr2 = sbest + log(1.0 - CERT_E2 / pbest);
        for (int g = 0; g < 25 && ok; ++g) {
          if ((mask & (1u << g)) && g != gbest) {
            int n = g * 4 + d;
            double a = pidot64(hr, Wpi, bpi, n);
            double p64 = fabs(a) + 1e-12;
            double s64 = log(p64) + (double)gmb[(size_t)(r0 + rw) * 100 + n];
            if (s64 + log(1.0 + CERT_E2 / p64) >= thr2) ok = false;
          }
        }
        if (ok) { idxsh[tid] = gbest; fsite[tid] = 0; }
      }
    }
  }
  __syncthreads();

  if (tid < 16) {
    if (fsite[tid * 4] | fsite[tid * 4 + 1] | fsite[tid * 4 + 2] | fsite[tid * 4 + 3]) {
      int p = atomicAdd(&nflag, 1);
      flagrows[p] = tid;
    }
  }

  // ---- Stage 5: selected mu/sigma dots, 2-way K-split over 256 threads ----
  {
    const int sub  = tid & 127;
    const int kh   = (tid >> 7) & 1;           // tid<128: 0, 128..255: 1
    const int head = __builtin_amdgcn_readfirstlane((sub >> 6) & 1);
    const int rem  = sub & 63;
    const int rw   = rem >> 2, d = rem & 3;
    float a = 0.f;
    if (tid < 256) {
      const int g = idxsh[rem];
      const int n = g * 4 + d;
      const float* Wh = head ? Wsg : Wmu;
      const float* bb = head ? bsg : bmu;
      const float* hr = h3f + rw * SA3 + kh * 100;
      const float* wp = Wh + (size_t)n * 200 + kh * 100;
      a = kh ? 0.f : bb[n];
#pragma unroll 2
      for (int k0 = 0; k0 < 100; k0 += 4) {
        float4 h4 = *(const float4*)(hr + k0);
        float4 w4 = *(const float4*)(wp + k0);
        a = fmaf(h4.x, w4.x, a);
        a = fmaf(h4.y, w4.y, a);
        a = fmaf(h4.z, w4.z, a);
        a = fmaf(h4.w, w4.w, a);
      }
      if (kh) sprt[sub] = a;
    }
    __syncthreads();
    if (tid < 128) {
      a += sprt[tid];
      if (head) sigsh[rem] = fabsf(a);
      else      mush [rem] = a;
    }
  }
  __syncthreads();

  // ---- Stage 6: store certified rows only ----
  if (tid < 64) {
    int rw = tid >> 2, d = tid & 3;
    unsigned char rowflag = fsite[rw * 4] | fsite[rw * 4 + 1] |
                            fsite[rw * 4 + 2] | fsite[rw * 4 + 3];
    if (!rowflag) {
      float rv = rnd[(size_t)(r0 + rw) * 4 + d];
      out[(size_t)(r0 + rw) * 4 + d] = fmaf(rv, sigsh[tid], mush[tid]);
    }
  }
  __syncthreads();   // pv/part dead; nflag/flagrows visible

  // ---- Stage 7: in-block fp64 repair of remaining flagged rows ----
  {
    double* rh1 = (double*)(smem + 8192);   // 128
    double* rh2 = rh1 + 128;           // 256
    double* rh3 = rh2 + 256;           // 200
    double* rsc = rh3 + 200;           // 100
    double* rmu = rsc + 100;           // 4
    double* rsg = rmu + 4;             // 4
    const int nf = nflag;
    for (int i = 0; i < nf; ++i) {
      const int row = r0 + flagrows[i];

      if (tid < 128) {
        double a = (double)b1[tid];
        a = fma((double)x0[(size_t)row * 3 + 0], (double)W1[tid * 3 + 0], a);
        a = fma((double)x0[(size_t)row * 3 + 1], (double)W1[tid * 3 + 1], a);
        a = fma((double)x0[(size_t)row * 3 + 2], (double)W1[tid * 3 + 2], a);
        rh1[tid] = fmax(a, 0.0);
      }
      __syncthreads();

      if (tid < 256) {
        double a = (double)b2[tid];
        const float* wq = W2 + (size_t)tid * 128;
        for (int k = 0; k < 128; k += 4) {
          float4 w4 = *(const float4*)(wq + k);
          a = fma(rh1[k],     (double)w4.x, a);
          a = fma(rh1[k + 1], (double)w4.y, a);
          a = fma(rh1[k + 2], (double)w4.z, a);
          a = fma(rh1[k + 3], (double)w4.w, a);
        }
        rh2[tid] = fmax(a, 0.0);
      }
      __syncthreads();

      if (tid < 200) {
        double a = (double)b3[tid];
        const float* wq = W3 + (size_t)tid * 256;
        for (int k = 0; k < 256; k += 4) {
          float4 w4 = *(const float4*)(wq + k);
          a = fma(rh2[k],     (double)w4.x, a);
          a = fma(rh2[k + 1], (double)w4.y, a);
          a = fma(rh2[k + 2], (double)w4.z, a);
          a = fma(rh2[k + 3], (double)w4.w, a);
        }
        rh3[tid] = fmax(a, 0.0);
      }
      __syncthreads();

      if (tid < 100) {
        double a = (double)bpi[tid];
        const float* wq = Wpi + (size_t)tid * 200;
        for (int k = 0; k < 200; k += 4) {
          float4 w4 = *(const float4*)(wq + k);
          a = fma(rh3[k],     (double)w4.x, a);
          a = fma(rh3[k + 1], (double)w4.y, a);
          a = fma(rh3[k + 2], (double)w4.z, a);
          a = fma(rh3[k + 3], (double)w4.w, a);
        }
        rsc[tid] = log(fabs(a) + 1e-12) + (double)gmb[(size_t)row * 100 + tid];
      }
      __syncthreads();

      if (tid < 4) {
        double best = rsc[tid]; int bi = 0;
        for (int g = 1; g < 25; ++g) {
          double s = rsc[g * 4 + tid];
          if (s > best) { best = s; bi = g; }
        }
        ridx[tid] = bi;
      }
      __syncthreads();

      if (tid < 8) {
        int head = tid >> 2, d = tid & 3;
        int n = ridx[d] * 4 + d;
        const float* Wh = head ? Wsg : Wmu;
        const float* bb = head ? bsg : bmu;
        double a = (double)bb[n];
        const float* wq = Wh + (size_t)n * 200;
        for (int k = 0; k < 200; k += 4) {
          float4 w4 = *(const float4*)(wq + k);
          a = fma(rh3[k],     (double)w4.x, a);
          a = fma(rh3[k + 1], (double)w4.y, a);
          a = fma(rh3[k + 2], (double)w4.z, a);
          a = fma(rh3[k + 3], (double)w4.w, a);
        }
        if (head) rsg[d] = fabs(a);
        else      rmu[d] = a;
      }
      __syncthreads();

      if (tid < 4) {
        double rv = (double)rnd[(size_t)row * 4 + tid];
        out[(size_t)row * 4 + tid] = (float)fma(rv, rsg[tid], rmu[tid]);
      }
      __syncthreads();
    }
  }
}

// ============================================================================
// Fallback: the proven fp32 kernel (32 rows/block; used if ws too small).
// ============================================================================

#define FB_NROWS 32
#define AOFF_H2  0
#define AOFF_H13 8320
#define AOFF_PS  14848
#define ALDS     18304

extern "C" __global__ void __launch_bounds__(512, 4)
fused_mdn_f32(const float* __restrict__ x0,  const float* __restrict__ rnd,
              const float* __restrict__ gmb,
              const float* __restrict__ W1,  const float* __restrict__ b1,
              const float* __restrict__ W2,  const float* __restrict__ b2,
              const float* __restrict__ W3,  const float* __restrict__ b3,
              const float* __restrict__ Wmu, const float* __restrict__ bmu,
              const float* __restrict__ Wsg, const float* __restrict__ bsg,
              const float* __restrict__ Wpi, const float* __restrict__ bpi,
              float* __restrict__ out)
{
  __shared__ __attribute__((aligned(16))) float lds[ALDS];
  __shared__ int   idxsh[128];
  __shared__ float mush[128];
  __shared__ float sigsh[128];
  __shared__ unsigned char fsite[128];
  __shared__ int   flagrows[32];
  __shared__ int   nflag;
  __shared__ int   ridx[4];

  const int tid = threadIdx.x;
  const int r0  = blockIdx.x * FB_NROWS;

  if (tid == 0) nflag = 0;

  float* h1 = lds + AOFF_H13;
  float* h2 = lds + AOFF_H2;
  float* h3 = lds + AOFF_H13;
  float* ps = lds + AOFF_PS;
  float* pv = lds + AOFF_H2;

  {
    int row = tid & 31, cg = tid >> 5;
    const float* xr = x0 + (size_t)(r0 + row) * 3;
    float xv0 = xr[0], xv1 = xr[1], xv2 = xr[2];
    int c0 = cg * 8;
#pragma unroll
    for (int c = 0; c < 8; ++c) {
      int col = c0 + c;
      float a = b1[col];
      a = fmaf(xv0, W1[col * 3 + 0], a);
      a = fmaf(xv1, W1[col * 3 + 1], a);
      a = fmaf(xv2, W1[col * 3 + 2], a);
      h1[row * SA1 + col] = fmaxf(a, 0.f);
    }
  }
  __syncthreads();

  {
    const int rq = tid & 7, cq = tid >> 3;
    float acc[4][4];
    tile_acc<128>(h1, SA1, W2, b2, rq, cq, acc);
#pragma unroll
    for (int r = 0; r < 4; ++r) {
      float4 o;
      o.x = fmaxf(acc[r][0], 0.f); o.y = fmaxf(acc[r][1], 0.f);
      o.z = fmaxf(acc[r][2], 0.f); o.w = fmaxf(acc[r][3], 0.f);
      *(float4*)(h2 + (rq + 8 * r) * SA2 + cq * 4) = o;
    }
  }
  __syncthreads();

  if (tid < 400) {
    const int rq = tid & 7, cq = tid >> 3;
    float acc[4][4];
    tile_acc<256>(h2, SA2, W3, b3, rq, cq, acc);
#pragma unroll
    for (int r = 0; r < 4; ++r) {
      float4 o;
      o.x = fmaxf(acc[r][0], 0.f); o.y = fmaxf(acc[r][1], 0.f);
      o.z = fmaxf(acc[r][2], 0.f); o.w = fmaxf(acc[r][3], 0.f);
      *(float4*)(h3 + (rq + 8 * r) * SA3 + cq * 4) = o;
    }
  }
  __syncthreads();

  if (tid < 200) {
    const int rq = tid & 7, cq = tid >> 3;
    float acc[4][4];
    tile_acc<200>(h3, SA3, Wpi, bpi, rq, cq, acc);
#pragma unroll
    for (int r = 0; r < 4; ++r) {
      int row = rq + 8 * r;
      float4 g4 = *(const float4*)(gmb + (size_t)(r0 + row) * 100 + cq * 4);
      float4 pq, sq;
      pq.x = fabsf(acc[r][0]) + 1e-12f; sq.x = logf(pq.x) + g4.x;
      pq.y = fabsf(acc[r][1]) + 1e-12f; sq.y = logf(pq.y) + g4.y;
      pq.z = fabsf(acc[r][2]) + 1e-12f; sq.z = logf(pq.z) + g4.z;
      pq.w = fabsf(acc[r][3]) + 1e-12f; sq.w = logf(pq.w) + g4.w;
      *(float4*)(pv + row * SP + cq * 4) = pq;
      *(float4*)(ps + row * SP + cq * 4) = sq;
    }
  }
  __syncthreads();

  if (tid < 128) {
    int rw = tid >> 2, d = tid & 3;
    const float* pr = ps + rw * SP + d;
    const float* qr = pv + rw * SP + d;
    float s1 = pr[0]; int g1 = 0;
#pragma unroll
    for (int g = 1; g < 25; ++g) {
      float s = pr[g * 4];
      if (s > s1) { s1 = s; g1 = g; }
    }
    unsigned char viol = 0;
    float p1 = qr[g1 * 4];
    if (p1 <= 2.f * CERT_E) {
      viol = 1;
    } else {
      float thr = s1 + logf(1.f - CERT_E / p1);
#pragma unroll
      for (int g = 0; g < 25; ++g) {
        if (g != g1) {
          float shi = pr[g * 4] + logf(1.f + CERT_E / qr[g * 4]);
          if (shi >= thr) viol = 1;
        }
      }
    }
    idxsh[tid] = g1;
    fsite[tid] = viol;
  }
  __syncthreads();

  if (tid < 32) {
    if (fsite[tid * 4] | fsite[tid * 4 + 1] | fsite[tid * 4 + 2] | fsite[tid * 4 + 3]) {
      int p = atomicAdd(&nflag, 1);
      flagrows[p] = tid;
    }
  }

  if (tid < 256) {
    int head = __builtin_amdgcn_readfirstlane(tid >> 7);
    int rem  = tid & 127;
    int rw   = rem >> 2, d = rem & 3;
    int g    = idxsh[rem];
    const float* Wh = head ? Wsg : Wmu;
    const float* bb = head ? bsg : bmu;
    int n = g * 4 + d;
    const float* hr = h3 + rw * SA3;
    const float* wp = Wh + (size_t)n * 200;
    float a = bb[n];
#pragma unroll 2
    for (int k0 = 0; k0 < 200; k0 += 4) {
      float4 h4 = *(const float4*)(hr + k0);
      float4 w4 = *(const float4*)(wp + k0);
      a = fmaf(h4.x, w4.x, a);
      a = fmaf(h4.y, w4.y, a);
      a = fmaf(h4.z, w4.z, a);
      a = fmaf(h4.w, w4.w, a);
    }
    if (head) sigsh[rem] = fabsf(a);
    else      mush [rem] = a;
  }
  __syncthreads();

  if (tid < 128) {
    int rw = tid >> 2, d = tid & 3;
    unsigned char rowflag = fsite[rw * 4] | fsite[rw * 4 + 1] |
                            fsite[rw * 4 + 2] | fsite[rw * 4 + 3];
    if (!rowflag) {
      float rv = rnd[(size_t)(r0 + rw) * 4 + d];
      out[(size_t)(r0 + rw) * 4 + d] = fmaf(rv, sigsh[tid], mush[tid]);
    }
  }
  __syncthreads();

  {
    double* rh1 = (double*)lds;
    double* rh2 = rh1 + 128;
    double* rh3 = rh2 + 256;
    double* rsc = rh3 + 200;
    double* rmu = rsc + 100;
    double* rsg = rmu + 4;
    const int nf = nflag;
    for (int i = 0; i < nf; ++i) {
      const int row = r0 + flagrows[i];

      if (tid < 128) {
        double a = (double)b1[tid];
        a = fma((double)x0[(size_t)row * 3 + 0], (double)W1[tid * 3 + 0], a);
        a = fma((double)x0[(size_t)row * 3 + 1], (double)W1[tid * 3 + 1], a);
        a = fma((double)x0[(size_t)row * 3 + 2], (double)W1[tid * 3 + 2], a);
        rh1[tid] = fmax(a, 0.0);
      }
      __syncthreads();

      if (tid < 256) {
        double a = (double)b2[tid];
        const float* wq = W2 + (size_t)tid * 128;
        for (int k = 0; k < 128; k += 4) {
          float4 w4 = *(const float4*)(wq + k);
          a = fma(rh1[k],     (double)w4.x, a);
          a = fma(rh1[k + 1], (double)w4.y, a);
          a = fma(rh1[k + 2], (double)w4.z, a);
          a = fma(rh1[k + 3], (double)w4.w, a);
        }
        rh2[tid] = fmax(a, 0.0);
      }
      __syncthreads();

      if (tid < 200) {
        double a = (double)b3[tid];
        const float* wq = W3 + (size_t)tid * 256;
        for (int k = 0; k < 256; k += 4) {
          float4 w4 = *(const float4*)(wq + k);
          a = fma(rh2[k],     (double)w4.x, a);
          a = fma(rh2[k + 1], (double)w4.y, a);
          a = fma(rh2[k + 2], (double)w4.z, a);
          a = fma(rh2[k + 3], (double)w4.w, a);
        }
        rh3[tid] = fmax(a, 0.0);
      }
      __syncthreads();

      if (tid < 100) {
        double a = (double)bpi[tid];
        const float* wq = Wpi + (size_t)tid * 200;
        for (int k = 0; k < 200; k += 4) {
          float4 w4 = *(const float4*)(wq + k);
          a = fma(rh3[k],     (double)w4.x, a);
          a = fma(rh3[k + 1], (double)w4.y, a);
          a = fma(rh3[k + 2], (double)w4.z, a);
          a = fma(rh3[k + 3], (double)w4.w, a);
        }
        rsc[tid] = log(fabs(a) + 1e-12) + (double)gmb[(size_t)row * 100 + tid];
      }
      __syncthreads();

      if (tid < 4) {
        double best = rsc[tid]; int bi = 0;
        for (int g = 1; g < 25; ++g) {
          double s = rsc[g * 4 + tid];
          if (s > best) { best = s; bi = g; }
        }
        ridx[tid] = bi;
      }
      __syncthreads();

      if (tid < 8) {
        int head = tid >> 2, d = tid & 3;
        int n = ridx[d] * 4 + d;
        const float* Wh = head ? Wsg : Wmu;
        const float* bb = head ? bsg : bmu;
        double a = (double)bb[n];
        const float* wq = Wh + (size_t)n * 200;
        for (int k = 0; k < 200; k += 4) {
          float4 w4 = *(const float4*)(wq + k);
          a = fma(rh3[k],     (double)w4.x, a);
          a = fma(rh3[k + 1], (double)w4.y, a);
          a = fma(rh3[k + 2], (double)w4.z, a);
          a = fma(rh3[k + 3], (double)w4.w, a);
        }
        if (head) rsg[d] = fabs(a);
        else      rmu[d] = a;
      }
      __syncthreads();

      if (tid < 4) {
        double rv = (double)rnd[(size_t)row * 4 + tid];
        out[(size_t)row * 4 + tid] = (float)fma(rv, rsg[tid], rmu[tid]);
      }
      __syncthreads();
    }
  }
}

// ============================================================================
extern "C" void kernel_launch(void* const* d_in, const int* in_sizes, int n_in,
                              void* d_out, int out_size, void* d_ws, size_t ws_size,
                              hipStream_t stream) {
  (void)out_size;
  float* out = (float*)d_out;

  static const int want[15] = {786432, 1048576, 26214400, 384, 128, 32768, 256,
                               51200, 200, 20000, 100, 20000, 100, 20000, 100};
  const float* p[15];
  bool used[64] = {false};
  bool ok = (n_in == 15);
  if (ok) {
    for (int j = 0; j < 15; ++j) {
      int found = -1;
      for (int i = 0; i < n_in; ++i)
        if (!used[i] && in_sizes[i] == want[j]) { found = i; break; }
      if (found < 0) { ok = false; break; }
      used[found] = true;
      p[j] = (const float*)d_in[found];
    }
  }
  if (!ok) return;

  if (d_ws && ws_size >= (size_t)WS_NEED) {
    mdn_prep<<<256, 256, 0, stream>>>(p[5], p[7], (unsigned char*)d_ws);
    fused_mdn_mfma<<<262144 / NROWS, 512, 0, stream>>>(
        p[0], p[1], p[2], p[3], p[4], p[5], p[6], p[7], p[8],
        p[9], p[10], p[11], p[12], p[13], p[14],
        (const unsigned char*)d_ws, out);
  } else {
    fused_mdn_f32<<<262144 / FB_NROWS, 512, 0, stream>>>(
        p[0], p[1], p[2], p[3], p[4], p[5], p[6], p[7], p[8],
        p[9], p[10], p[11], p[12], p[13], p[14], out);
  }
}

// Round 9
// 1010.494 us; speedup vs baseline: 1.5285x; 1.5285x over previous
//
#include <hip/hip_runtime.h>
#include <hip/hip_bf16.h>
#include <stdint.h>
#include <math.h>

// ============================================================================
// R9 = R5 (best, 970us) with ONE change: __launch_bounds__(512,4) -> (512,2).
// R5/R8 A/B isolated a ~34us/block row-independent cost = the 464KB/block
// B-operand L2 streams (W2+W3 hi/lo + Wpi). At 2 blocks/CU and ~7
// outstanding 16B loads/wave (VGPR=64 budget, compiler pinned at cap),
// issue capacity ~7.2 B/cy/CU -> 15MB/CU -> ~2.1M cy = the measured wall.
// (512,2) keeps the same LDS-capped 2-block residency but doubles the VGPR
// budget to 128 -> deeper load pipelining -> ~2x bytes in flight.
// Everything else byte-identical to R5 (passed, absmax 9.77e-4).
// ============================================================================

typedef _Float16 f16x8 __attribute__((ext_vector_type(8)));
typedef float    f32x4 __attribute__((ext_vector_type(4)));

#define NROWS 32
#define CERT_E  5e-5f
#define CERT_E2 2e-5

// ws plane offsets (bytes). Planes are row-major [N][K] fp16.
#define OW2H 0          // W2  [256][128]
#define OW2L 65536
#define OW3H 131072     // W3  [256][256]  (rows 200..255 zero)
#define OW3L 262144
#define WS_NEED 393216

#define SA1 132
#define SA2 260
#define SA3 204
#define SP  108

__device__ __forceinline__ void split16(float v, _Float16& hi, _Float16& lo) {
  hi = (_Float16)v;
  lo = (_Float16)((v - (float)hi) * 2048.f);
}

// R9-proven fp32 4x4 tile body (no spills).
template<int K>
__device__ __forceinline__ void tile_acc(const float* __restrict__ hbase, int hstride,
                                         const float* __restrict__ W,
                                         const float* __restrict__ bias,
                                         int rq, int cq, float acc[4][4]) {
  float4 bv = *(const float4*)(bias + cq * 4);
#pragma unroll
  for (int r = 0; r < 4; ++r) {
    acc[r][0] = bv.x; acc[r][1] = bv.y; acc[r][2] = bv.z; acc[r][3] = bv.w;
  }
  const float* h0 = hbase + rq * hstride;
#pragma unroll 2
  for (int k = 0; k < K; k += 4) {
    float4 h4[4];
#pragma unroll
    for (int r = 0; r < 4; ++r) h4[r] = *(const float4*)(h0 + (r * 8) * hstride + k);
#pragma unroll
    for (int c = 0; c < 4; ++c) {
      float4 w4 = *(const float4*)(W + (size_t)(cq * 4 + c) * K + k);
#pragma unroll
      for (int r = 0; r < 4; ++r) {
        acc[r][c] = fmaf(h4[r].x, w4.x, acc[r][c]);
        acc[r][c] = fmaf(h4[r].y, w4.y, acc[r][c]);
        acc[r][c] = fmaf(h4[r].z, w4.z, acc[r][c]);
        acc[r][c] = fmaf(h4[r].w, w4.w, acc[r][c]);
      }
    }
  }
}

// Partial-K variant: acc pre-initialized by caller; W row stride WSTR != K.
template<int K, int WSTR>
__device__ __forceinline__ void tile_part(const float* __restrict__ hbase, int hstride,
                                          const float* __restrict__ W,
                                          int rq, int cq, float acc[4][4]) {
  const float* h0 = hbase + rq * hstride;
#pragma unroll 2
  for (int k = 0; k < K; k += 4) {
    float4 h4[4];
#pragma unroll
    for (int r = 0; r < 4; ++r) h4[r] = *(const float4*)(h0 + (r * 8) * hstride + k);
#pragma unroll
    for (int c = 0; c < 4; ++c) {
      float4 w4 = *(const float4*)(W + (size_t)(cq * 4 + c) * WSTR + k);
#pragma unroll
      for (int r = 0; r < 4; ++r) {
        acc[r][c] = fmaf(h4[r].x, w4.x, acc[r][c]);
        acc[r][c] = fmaf(h4[r].y, w4.y, acc[r][c]);
        acc[r][c] = fmaf(h4[r].z, w4.z, acc[r][c]);
        acc[r][c] = fmaf(h4[r].w, w4.w, acc[r][c]);
      }
    }
  }
}

// fp64-accum pi dot over LDS fp32 h3 row (tier-2 cert).
__device__ __forceinline__ double pidot64(const float* __restrict__ hr,
                                          const float* __restrict__ Wpi,
                                          const float* __restrict__ bpi, int n) {
  double a = (double)bpi[n];
  const float* wq = Wpi + (size_t)n * 200;
  for (int k = 0; k < 200; k += 4) {
    float4 w4 = *(const float4*)(wq + k);
    a = fma((double)hr[k],     (double)w4.x, a);
    a = fma((double)hr[k + 1], (double)w4.y, a);
    a = fma((double)hr[k + 2], (double)w4.z, a);
    a = fma((double)hr[k + 3], (double)w4.w, a);
  }
  return a;
}

// ---------------------------------------------------------------------------
// Prep: split W2/W3 into fp16 hi / scaled-lo planes in workspace.
// ---------------------------------------------------------------------------
extern "C" __global__ void mdn_prep(const float* __restrict__ W2,
                                    const float* __restrict__ W3,
                                    unsigned char* __restrict__ ws) {
  const int stride = gridDim.x * blockDim.x;
  const int gid = blockIdx.x * blockDim.x + threadIdx.x;

  _Float16* w2h = (_Float16*)(ws + OW2H);
  _Float16* w2l = (_Float16*)(ws + OW2L);
  for (int e = gid; e < 256 * 128; e += stride) {
    _Float16 h, l; split16(W2[e], h, l);
    w2h[e] = h; w2l[e] = l;
  }

  _Float16* w3h = (_Float16*)(ws + OW3H);
  _Float16* w3l = (_Float16*)(ws + OW3L);
  for (int e = gid; e < 256 * 256; e += stride) {
    int n = e >> 8;
    float x = (n < 200) ? W3[e] : 0.f;
    _Float16 h, l; split16(x, h, l);
    w3h[e] = h; w3l[e] = l;
  }
}

// ---------------------------------------------------------------------------
// Main kernel. 512 threads, 32 rows/block, ~75.3KB LDS -> 2 blocks/CU.
// Fragment layout (A-operand, per plane):
//   byte = ((rowblk*NKT + kt)*64 + ((k>>3)&3)*16 + (row&15))*16 + (k&7)*2
// ---------------------------------------------------------------------------
extern "C" __global__ void __launch_bounds__(512, 2)
fused_mdn_mfma(const float* __restrict__ x0,  const float* __restrict__ rnd,
               const float* __restrict__ gmb,
               const float* __restrict__ W1,  const float* __restrict__ b1,
               const float* __restrict__ W2,  const float* __restrict__ b2,
               const float* __restrict__ W3,  const float* __restrict__ b3,
               const float* __restrict__ Wmu, const float* __restrict__ bmu,
               const float* __restrict__ Wsg, const float* __restrict__ bsg,
               const float* __restrict__ Wpi, const float* __restrict__ bpi,
               const unsigned char* __restrict__ ws,
               float* __restrict__ out)
{
  // smem map:
  //   [0,32768)      regA: h2 fragments (hi 16K | lo 16K).
  //                  After stage 3: pv (13824 B) at +0; stage-4 partials
  //                  [16][200] (12800 B) at +16384; stage-5 partials (1KB)
  //                  at +16384; repair doubles at +16384.
  //   [32768,58880)  h3f: fp32 h3 [32][204]
  //   [58880,75264)  regC: h1 fragments (hi 8K | lo 8K); after stage 2: ps
  __shared__ __attribute__((aligned(16))) unsigned char smem[75264];
  __shared__ int   idxsh[128];
  __shared__ float mush[128];
  __shared__ float sigsh[128];
  __shared__ unsigned char fsite[128];
  __shared__ int   flagrows[32];
  __shared__ int   nflag;
  __shared__ int   ridx[4];

  unsigned char* regA = smem;
  unsigned char* regC = smem + 58880;
  float* h3f  = (float*)(smem + 32768);
  float* pv   = (float*)smem;
  float* ps   = (float*)(smem + 58880);
  float* part = (float*)(smem + 16384);   // stage-4 partials [16][200]
  float* sprt = (float*)(smem + 16384);   // stage-5 partials [256]

  const int tid  = threadIdx.x;
  const int lane = tid & 63;
  const int w    = tid >> 6;     // wave 0..7
  const int ln   = lane & 15;    // non-k dim selector
  const int ks   = lane >> 4;    // k sub-block 0..3
  const int r0   = blockIdx.x * NROWS;

  if (tid == 0) nflag = 0;

  // ---- Stage 1: h1 = relu(x0 @ W1^T + b1), K=3 -> h1frag in regC ----
  {
    int row = tid & 31, cg = tid >> 5;       // 8 cols per thread
    const float* xr = x0 + (size_t)(r0 + row) * 3;
    float xv0 = xr[0], xv1 = xr[1], xv2 = xr[2];
    int c0 = cg * 8;
    f16x8 vh, vl;
#pragma unroll
    for (int c = 0; c < 8; ++c) {
      int col = c0 + c;
      float a = b1[col];
      a = fmaf(xv0, W1[col * 3 + 0], a);
      a = fmaf(xv1, W1[col * 3 + 1], a);
      a = fmaf(xv2, W1[col * 3 + 2], a);
      a = fmaxf(a, 0.f);
      _Float16 h, l; split16(a, h, l);
      vh[c] = h; vl[c] = l;
    }
    int kt = c0 >> 5, sub = (c0 >> 3) & 3;
    int off = (((row >> 4) * 4 + kt) * 64 + sub * 16 + (row & 15)) * 16;
    *(f16x8*)(regC + off)        = vh;
    *(f16x8*)(regC + 8192 + off) = vl;
  }
  __syncthreads();

  // ---- Stage 2: h2 = relu(h1 @ W2^T + b2)  M=32 N=256 K=128 (NKT=4) ----
  {
    f32x4 a1[2][2], a2[2][2];                 // [cbi][rb]
#pragma unroll
    for (int i = 0; i < 2; ++i)
#pragma unroll
      for (int j = 0; j < 2; ++j) {
        a1[i][j] = (f32x4){0.f, 0.f, 0.f, 0.f};
        a2[i][j] = (f32x4){0.f, 0.f, 0.f, 0.f};
      }
    const unsigned char* bp0 = ws + OW2H + (size_t)((w       * 16 + ln) * 256) + ks * 16;
    const unsigned char* bp1 = ws + OW2H + (size_t)(((w + 8) * 16 + ln) * 256) + ks * 16;
#pragma unroll
    for (int kt = 0; kt < 4; ++kt) {
      int ao = (kt * 64 + lane) * 16;
      f16x8 Ah0 = *(const f16x8*)(regC + ao);
      f16x8 Al0 = *(const f16x8*)(regC + 8192 + ao);
      f16x8 Ah1 = *(const f16x8*)(regC + ao + 4096);
      f16x8 Al1 = *(const f16x8*)(regC + 8192 + ao + 4096);
      {
        f16x8 Bh = *(const f16x8*)(bp0 + kt * 64);
        f16x8 Bl = *(const f16x8*)(bp0 + 65536 + kt * 64);
        a1[0][0] = __builtin_amdgcn_mfma_f32_16x16x32_f16(Ah0, Bh, a1[0][0], 0, 0, 0);
        a2[0][0] = __builtin_amdgcn_mfma_f32_16x16x32_f16(Ah0, Bl, a2[0][0], 0, 0, 0);
        a2[0][0] = __builtin_amdgcn_mfma_f32_16x16x32_f16(Al0, Bh, a2[0][0], 0, 0, 0);
        a1[0][1] = __builtin_amdgcn_mfma_f32_16x16x32_f16(Ah1, Bh, a1[0][1], 0, 0, 0);
        a2[0][1] = __builtin_amdgcn_mfma_f32_16x16x32_f16(Ah1, Bl, a2[0][1], 0, 0, 0);
        a2[0][1] = __builtin_amdgcn_mfma_f32_16x16x32_f16(Al1, Bh, a2[0][1], 0, 0, 0);
      }
      {
        f16x8 Bh = *(const f16x8*)(bp1 + kt * 64);
        f16x8 Bl = *(const f16x8*)(bp1 + 65536 + kt * 64);
        a1[1][0] = __builtin_amdgcn_mfma_f32_16x16x32_f16(Ah0, Bh, a1[1][0], 0, 0, 0);
        a2[1][0] = __builtin_amdgcn_mfma_f32_16x16x32_f16(Ah0, Bl, a2[1][0], 0, 0, 0);
        a2[1][0] = __builtin_amdgcn_mfma_f32_16x16x32_f16(Al0, Bh, a2[1][0], 0, 0, 0);
        a1[1][1] = __builtin_amdgcn_mfma_f32_16x16x32_f16(Ah1, Bh, a1[1][1], 0, 0, 0);
        a2[1][1] = __builtin_amdgcn_mfma_f32_16x16x32_f16(Ah1, Bl, a2[1][1], 0, 0, 0);
        a2[1][1] = __builtin_amdgcn_mfma_f32_16x16x32_f16(Al1, Bh, a2[1][1], 0, 0, 0);
      }
    }
#pragma unroll
    for (int cbi = 0; cbi < 2; ++cbi) {
      int col = (w + cbi * 8) * 16 + ln;                  // 0..255
      float bb = b2[col];
      int kt2 = col >> 5, sub2 = (col >> 3) & 3, j2 = col & 7;
#pragma unroll
      for (int rb = 0; rb < 2; ++rb)
#pragma unroll
        for (int r = 0; r < 4; ++r) {
          float v = a1[cbi][rb][r] + a2[cbi][rb][r] * (1.f / 2048.f) + bb;
          v = fmaxf(v, 0.f);
          _Float16 h, l; split16(v, h, l);
          int off = ((rb * 8 + kt2) * 64 + sub2 * 16 + (ks * 4 + r)) * 16 + j2 * 2;
          *(_Float16*)(regA + off)         = h;
          *(_Float16*)(regA + 16384 + off) = l;
        }
    }
  }
  __syncthreads();

  // ---- Gumbel prefetch for stage 4 (hidden under stage-3 MFMA) ----
  float4 g4pre[4];
  if (tid < 200) {
    const int rq = tid & 7, cq = tid >> 3;
#pragma unroll
    for (int r = 0; r < 4; ++r)
      g4pre[r] = *(const float4*)(gmb + (size_t)(r0 + rq + 8 * r) * 100 + cq * 4);
  }

  // ---- Stage 3: h3 = relu(h2 @ W3^T + b3) -> PLAIN FP32 h3f[32][204] ----
  {
    f32x4 a1[2][2], a2[2][2];
#pragma unroll
    for (int i = 0; i < 2; ++i)
#pragma unroll
      for (int j = 0; j < 2; ++j) {
        a1[i][j] = (f32x4){0.f, 0.f, 0.f, 0.f};
        a2[i][j] = (f32x4){0.f, 0.f, 0.f, 0.f};
      }
    const unsigned char* bp0 = ws + OW3H + (size_t)((w       * 16 + ln) * 512) + ks * 16;
    const unsigned char* bp1 = ws + OW3H + (size_t)(((w + 8) * 16 + ln) * 512) + ks * 16;
#pragma unroll
    for (int kt = 0; kt < 8; ++kt) {
      int ao = (kt * 64 + lane) * 16;
      f16x8 Ah0 = *(const f16x8*)(regA + ao);
      f16x8 Al0 = *(const f16x8*)(regA + 16384 + ao);
      f16x8 Ah1 = *(const f16x8*)(regA + ao + 8192);
      f16x8 Al1 = *(const f16x8*)(regA + 16384 + ao + 8192);
      {
        f16x8 Bh = *(const f16x8*)(bp0 + kt * 64);
        f16x8 Bl = *(const f16x8*)(bp0 + 131072 + kt * 64);
        a1[0][0] = __builtin_amdgcn_mfma_f32_16x16x32_f16(Ah0, Bh, a1[0][0], 0, 0, 0);
        a2[0][0] = __builtin_amdgcn_mfma_f32_16x16x32_f16(Ah0, Bl, a2[0][0], 0, 0, 0);
        a2[0][0] = __builtin_amdgcn_mfma_f32_16x16x32_f16(Al0, Bh, a2[0][0], 0, 0, 0);
        a1[0][1] = __builtin_amdgcn_mfma_f32_16x16x32_f16(Ah1, Bh, a1[0][1], 0, 0, 0);
        a2[0][1] = __builtin_amdgcn_mfma_f32_16x16x32_f16(Ah1, Bl, a2[0][1], 0, 0, 0);
        a2[0][1] = __builtin_amdgcn_mfma_f32_16x16x32_f16(Al1, Bh, a2[0][1], 0, 0, 0);
      }
      {
        f16x8 Bh = *(const f16x8*)(bp1 + kt * 64);
        f16x8 Bl = *(const f16x8*)(bp1 + 131072 + kt * 64);
        a1[1][0] = __builtin_amdgcn_mfma_f32_16x16x32_f16(Ah0, Bh, a1[1][0], 0, 0, 0);
        a2[1][0] = __builtin_amdgcn_mfma_f32_16x16x32_f16(Ah0, Bl, a2[1][0], 0, 0, 0);
        a2[1][0] = __builtin_amdgcn_mfma_f32_16x16x32_f16(Al0, Bh, a2[1][0], 0, 0, 0);
        a1[1][1] = __builtin_amdgcn_mfma_f32_16x16x32_f16(Ah1, Bh, a1[1][1], 0, 0, 0);
        a2[1][1] = __builtin_amdgcn_mfma_f32_16x16x32_f16(Ah1, Bl, a2[1][1], 0, 0, 0);
        a2[1][1] = __builtin_amdgcn_mfma_f32_16x16x32_f16(Al1, Bh, a2[1][1], 0, 0, 0);
      }
    }
#pragma unroll
    for (int cbi = 0; cbi < 2; ++cbi) {
      int col = (w + cbi * 8) * 16 + ln;                  // 0..255; keep <200
      if (col < 200) {
        float bb = b3[col];
#pragma unroll
        for (int rb = 0; rb < 2; ++rb)
#pragma unroll
          for (int r = 0; r < 4; ++r) {
            float v = a1[cbi][rb][r] + a2[cbi][rb][r] * (1.f / 2048.f) + bb;
            h3f[(rb * 16 + ks * 4 + r) * SA3 + col] = fmaxf(v, 0.f);
          }
      }
    }
  }
  __syncthreads();

  // ---- Stage 4: pi head, 2-way K-split over 400 threads ----
  {
    float acc[4][4];
    if (tid < 400) {
      const int t  = (tid < 200) ? tid : tid - 200;
      const int kh = (tid >= 200) ? 1 : 0;
      const int rq = t & 7, cq = t >> 3;      // cq 0..24
      if (kh == 0) {
        float4 bv = *(const float4*)(bpi + cq * 4);
#pragma unroll
        for (int r = 0; r < 4; ++r) {
          acc[r][0] = bv.x; acc[r][1] = bv.y; acc[r][2] = bv.z; acc[r][3] = bv.w;
        }
      } else {
#pragma unroll
        for (int r = 0; r < 4; ++r)
          acc[r][0] = acc[r][1] = acc[r][2] = acc[r][3] = 0.f;
      }
      tile_part<100, 200>(h3f + kh * 100, SA3, Wpi + kh * 100, rq, cq, acc);
      if (kh) {
#pragma unroll
        for (int r = 0; r < 4; ++r)
#pragma unroll
          for (int c = 0; c < 4; ++c)
            part[(r * 4 + c) * 200 + t] = acc[r][c];    // transposed: conflict-free
      }
    }
    __syncthreads();
    if (tid < 200) {
      const int rq = tid & 7, cq = tid >> 3;
#pragma unroll
      for (int r = 0; r < 4; ++r)
#pragma unroll
        for (int c = 0; c < 4; ++c)
          acc[r][c] += part[(r * 4 + c) * 200 + tid];
#pragma unroll
      for (int r = 0; r < 4; ++r) {
        int row = rq + 8 * r;
        float4 g4 = g4pre[r];
        float4 pq, sq;
        pq.x = fabsf(acc[r][0]) + 1e-12f; sq.x = logf(pq.x) + g4.x;
        pq.y = fabsf(acc[r][1]) + 1e-12f; sq.y = logf(pq.y) + g4.y;
        pq.z = fabsf(acc[r][2]) + 1e-12f; sq.z = logf(pq.z) + g4.z;
        pq.w = fabsf(acc[r][3]) + 1e-12f; sq.w = logf(pq.w) + g4.w;
        *(float4*)(pv + row * SP + cq * 4) = pq;
        *(float4*)(ps + row * SP + cq * 4) = sq;
      }
    }
  }
  __syncthreads();

  // ---- Stage 4.5: argmax + tier-1 interval certification per (row,d) ----
  if (tid < 128) {
    int rw = tid >> 2, d = tid & 3;
    const float* pr = ps + rw * SP + d;
    const float* qr = pv + rw * SP + d;
    float s1 = pr[0]; int g1 = 0;
#pragma unroll
    for (int g = 1; g < 25; ++g) {
      float s = pr[g * 4];
      if (s > s1) { s1 = s; g1 = g; }     // strict > == first-occurrence argmax
    }
    unsigned char viol = 0;
    float p1 = qr[g1 * 4];
    if (p1 <= 2.f * CERT_E) {
      viol = 1;
    } else {
      float thr = s1 + logf(1.f - CERT_E / p1);
#pragma unroll
      for (int g = 0; g < 25; ++g) {
        if (g != g1) {
          float shi = pr[g * 4] + logf(1.f + CERT_E / qr[g * 4]);
          if (shi >= thr) viol = 1;
        }
      }
    }
    idxsh[tid] = g1;
    fsite[tid] = viol;
  }
  __syncthreads();

  // ---- Stage 4.6: tier-2 fp64-accum re-cert of flagged sites ----
  if (tid < 128 && fsite[tid]) {
    int rw = tid >> 2, d = tid & 3;
    const float* pr = ps + rw * SP + d;
    const float* qr = pv + rw * SP + d;
    const float* hr = h3f + rw * SA3;
    int g1 = idxsh[tid];
    float p1 = qr[g1 * 4];
    if (p1 > 2.f * CERT_E) {
      float s1 = pr[g1 * 4];
      float thr = s1 + logf(1.f - CERT_E / p1);
      unsigned mask = 1u << g1;
#pragma unroll
      for (int g = 0; g < 25; ++g) {
        if (g != g1) {
          float shi = pr[g * 4] + logf(1.f + CERT_E / qr[g * 4]);
          if (shi >= thr) mask |= (1u << g);
        }
      }
      double sbest = 0.0, pbest = 0.0; int gbest = -1;
      for (int g = 0; g < 25; ++g) {
        if (mask & (1u << g)) {
          int n = g * 4 + d;
          double a = pidot64(hr, Wpi, bpi, n);
          double p64 = fabs(a) + 1e-12;
          double s64 = log(p64) + (double)gmb[(size_t)(r0 + rw) * 100 + n];
          if (gbest < 0 || s64 > sbest) { sbest = s64; pbest = p64; gbest = g; }
        }
      }
      bool ok = (pbest > 2.0 * CERT_E2);
      if (ok) {
        double thr2 = sbest + log(1.0 - CERT_E2 / pbest);
        for (int g = 0; g < 25 && ok; ++g) {
          if ((mask & (1u << g)) && g != gbest) {
            int n = g * 4 + d;
            double a = pidot64(hr, Wpi, bpi, n);
            double p64 = fabs(a) + 1e-12;
            double s64 = log(p64) + (double)gmb[(size_t)(r0 + rw) * 100 + n];
            if (s64 + log(1.0 + CERT_E2 / p64) >= thr2) ok = false;
          }
        }
        if (ok) { idxsh[tid] = gbest; fsite[tid] = 0; }
      }
    }
  }
  __syncthreads();

  if (tid < 32) {
    if (fsite[tid * 4] | fsite[tid * 4 + 1] | fsite[tid * 4 + 2] | fsite[tid * 4 + 3]) {
      int p = atomicAdd(&nflag, 1);
      flagrows[p] = tid;
    }
  }

  // ---- Stage 5: selected mu/sigma dots, 2-way K-split over 512 threads ----
  {
    const int kh   = tid >> 8;                 // 0 or 1
    const int sub  = tid & 255;
    const int head = __builtin_amdgcn_readfirstlane(sub >> 7);
    const int rem  = sub & 127;
    const int rw   = rem >> 2, d = rem & 3;
    const int g    = idxsh[rem];
    const int n    = g * 4 + d;
    const float* Wh = head ? Wsg : Wmu;
    const float* bb = head ? bsg : bmu;
    const float* hr = h3f + rw * SA3 + kh * 100;
    const float* wp = Wh + (size_t)n * 200 + kh * 100;
    float a = kh ? 0.f : bb[n];
#pragma unroll 2
    for (int k0 = 0; k0 < 100; k0 += 4) {
      float4 h4 = *(const float4*)(hr + k0);
      float4 w4 = *(const float4*)(wp + k0);
      a = fmaf(h4.x, w4.x, a);
      a = fmaf(h4.y, w4.y, a);
      a = fmaf(h4.z, w4.z, a);
      a = fmaf(h4.w, w4.w, a);
    }
    if (kh) sprt[sub] = a;
    __syncthreads();
    if (tid < 256) {
      a += sprt[tid];
      if (head) sigsh[rem] = fabsf(a);
      else      mush [rem] = a;
    }
  }
  __syncthreads();

  // ---- Stage 6: store certified rows only ----
  if (tid < 128) {
    int rw = tid >> 2, d = tid & 3;
    unsigned char rowflag = fsite[rw * 4] | fsite[rw * 4 + 1] |
                            fsite[rw * 4 + 2] | fsite[rw * 4 + 3];
    if (!rowflag) {
      float rv = rnd[(size_t)(r0 + rw) * 4 + d];
      out[(size_t)(r0 + rw) * 4 + d] = fmaf(rv, sigsh[tid], mush[tid]);
    }
  }
  __syncthreads();   // smem regA region dead; nflag/flagrows visible

  // ---- Stage 7: in-block fp64 repair of remaining flagged rows ----
  {
    double* rh1 = (double*)(smem + 16384);   // 128
    double* rh2 = rh1 + 128;           // 256
    double* rh3 = rh2 + 256;           // 200
    double* rsc = rh3 + 200;           // 100
    double* rmu = rsc + 100;           // 4
    double* rsg = rmu + 4;             // 4
    const int nf = nflag;
    for (int i = 0; i < nf; ++i) {
      const int row = r0 + flagrows[i];

      if (tid < 128) {
        double a = (double)b1[tid];
        a = fma((double)x0[(size_t)row * 3 + 0], (double)W1[tid * 3 + 0], a);
        a = fma((double)x0[(size_t)row * 3 + 1], (double)W1[tid * 3 + 1], a);
        a = fma((double)x0[(size_t)row * 3 + 2], (double)W1[tid * 3 + 2], a);
        rh1[tid] = fmax(a, 0.0);
      }
      __syncthreads();

      if (tid < 256) {
        double a = (double)b2[tid];
        const float* wq = W2 + (size_t)tid * 128;
        for (int k = 0; k < 128; k += 4) {
          float4 w4 = *(const float4*)(wq + k);
          a = fma(rh1[k],     (double)w4.x, a);
          a = fma(rh1[k + 1], (double)w4.y, a);
          a = fma(rh1[k + 2], (double)w4.z, a);
          a = fma(rh1[k + 3], (double)w4.w, a);
        }
        rh2[tid] = fmax(a, 0.0);
      }
      __syncthreads();

      if (tid < 200) {
        double a = (double)b3[tid];
        const float* wq = W3 + (size_t)tid * 256;
        for (int k = 0; k < 256; k += 4) {
          float4 w4 = *(const float4*)(wq + k);
          a = fma(rh2[k],     (double)w4.x, a);
          a = fma(rh2[k + 1], (double)w4.y, a);
          a = fma(rh2[k + 2], (double)w4.z, a);
          a = fma(rh2[k + 3], (double)w4.w, a);
        }
        rh3[tid] = fmax(a, 0.0);
      }
      __syncthreads();

      if (tid < 100) {
        double a = (double)bpi[tid];
        const float* wq = Wpi + (size_t)tid * 200;
        for (int k = 0; k < 200; k += 4) {
          float4 w4 = *(const float4*)(wq + k);
          a = fma(rh3[k],     (double)w4.x, a);
          a = fma(rh3[k + 1], (double)w4.y, a);
          a = fma(rh3[k + 2], (double)w4.z, a);
          a = fma(rh3[k + 3], (double)w4.w, a);
        }
        rsc[tid] = log(fabs(a) + 1e-12) + (double)gmb[(size_t)row * 100 + tid];
      }
      __syncthreads();

      if (tid < 4) {
        double best = rsc[tid]; int bi = 0;
        for (int g = 1; g < 25; ++g) {
          double s = rsc[g * 4 + tid];
          if (s > best) { best = s; bi = g; }
        }
        ridx[tid] = bi;
      }
      __syncthreads();

      if (tid < 8) {
        int head = tid >> 2, d = tid & 3;
        int n = ridx[d] * 4 + d;
        const float* Wh = head ? Wsg : Wmu;
        const float* bb = head ? bsg : bmu;
        double a = (double)bb[n];
        const float* wq = Wh + (size_t)n * 200;
        for (int k = 0; k < 200; k += 4) {
          float4 w4 = *(const float4*)(wq + k);
          a = fma(rh3[k],     (double)w4.x, a);
          a = fma(rh3[k + 1], (double)w4.y, a);
          a = fma(rh3[k + 2], (double)w4.z, a);
          a = fma(rh3[k + 3], (double)w4.w, a);
        }
        if (head) rsg[d] = fabs(a);
        else      rmu[d] = a;
      }
      __syncthreads();

      if (tid < 4) {
        double rv = (double)rnd[(size_t)row * 4 + tid];
        out[(size_t)row * 4 + tid] = (float)fma(rv, rsg[tid], rmu[tid]);
      }
      __syncthreads();
    }
  }
}

// ============================================================================
// Fallback: the proven fp32 kernel (used only if ws_size < WS_NEED).
// ============================================================================

#define AOFF_H2  0
#define AOFF_H13 8320
#define AOFF_PS  14848
#define ALDS     18304

extern "C" __global__ void __launch_bounds__(512, 4)
fused_mdn_f32(const float* __restrict__ x0,  const float* __restrict__ rnd,
              const float* __restrict__ gmb,
              const float* __restrict__ W1,  const float* __restrict__ b1,
              const float* __restrict__ W2,  const float* __restrict__ b2,
              const float* __restrict__ W3,  const float* __restrict__ b3,
              const float* __restrict__ Wmu, const float* __restrict__ bmu,
              const float* __restrict__ Wsg, const float* __restrict__ bsg,
              const float* __restrict__ Wpi, const float* __restrict__ bpi,
              float* __restrict__ out)
{
  __shared__ __attribute__((aligned(16))) float lds[ALDS];
  __shared__ int   idxsh[128];
  __shared__ float mush[128];
  __shared__ float sigsh[128];
  __shared__ unsigned char fsite[128];
  __shared__ int   flagrows[32];
  __shared__ int   nflag;
  __shared__ int   ridx[4];

  const int tid = threadIdx.x;
  const int r0  = blockIdx.x * 32;

  if (tid == 0) nflag = 0;

  float* h1 = lds + AOFF_H13;
  float* h2 = lds + AOFF_H2;
  float* h3 = lds + AOFF_H13;
  float* ps = lds + AOFF_PS;
  float* pv = lds + AOFF_H2;

  {
    int row = tid & 31, cg = tid >> 5;
    const float* xr = x0 + (size_t)(r0 + row) * 3;
    float xv0 = xr[0], xv1 = xr[1], xv2 = xr[2];
    int c0 = cg * 8;
#pragma unroll
    for (int c = 0; c < 8; ++c) {
      int col = c0 + c;
      float a = b1[col];
      a = fmaf(xv0, W1[col * 3 + 0], a);
      a = fmaf(xv1, W1[col * 3 + 1], a);
      a = fmaf(xv2, W1[col * 3 + 2], a);
      h1[row * SA1 + col] = fmaxf(a, 0.f);
    }
  }
  __syncthreads();

  {
    const int rq = tid & 7, cq = tid >> 3;
    float acc[4][4];
    tile_acc<128>(h1, SA1, W2, b2, rq, cq, acc);
#pragma unroll
    for (int r = 0; r < 4; ++r) {
      float4 o;
      o.x = fmaxf(acc[r][0], 0.f); o.y = fmaxf(acc[r][1], 0.f);
      o.z = fmaxf(acc[r][2], 0.f); o.w = fmaxf(acc[r][3], 0.f);
      *(float4*)(h2 + (rq + 8 * r) * SA2 + cq * 4) = o;
    }
  }
  __syncthreads();

  if (tid < 400) {
    const int rq = tid & 7, cq = tid >> 3;
    float acc[4][4];
    tile_acc<256>(h2, SA2, W3, b3, rq, cq, acc);
#pragma unroll
    for (int r = 0; r < 4; ++r) {
      float4 o;
      o.x = fmaxf(acc[r][0], 0.f); o.y = fmaxf(acc[r][1], 0.f);
      o.z = fmaxf(acc[r][2], 0.f); o.w = fmaxf(acc[r][3], 0.f);
      *(float4*)(h3 + (rq + 8 * r) * SA3 + cq * 4) = o;
    }
  }
  __syncthreads();

  if (tid < 200) {
    const int rq = tid & 7, cq = tid >> 3;
    float acc[4][4];
    tile_acc<200>(h3, SA3, Wpi, bpi, rq, cq, acc);
#pragma unroll
    for (int r = 0; r < 4; ++r) {
      int row = rq + 8 * r;
      float4 g4 = *(const float4*)(gmb + (size_t)(r0 + row) * 100 + cq * 4);
      float4 pq, sq;
      pq.x = fabsf(acc[r][0]) + 1e-12f; sq.x = logf(pq.x) + g4.x;
      pq.y = fabsf(acc[r][1]) + 1e-12f; sq.y = logf(pq.y) + g4.y;
      pq.z = fabsf(acc[r][2]) + 1e-12f; sq.z = logf(pq.z) + g4.z;
      pq.w = fabsf(acc[r][3]) + 1e-12f; sq.w = logf(pq.w) + g4.w;
      *(float4*)(pv + row * SP + cq * 4) = pq;
      *(float4*)(ps + row * SP + cq * 4) = sq;
    }
  }
  __syncthreads();

  if (tid < 128) {
    int rw = tid >> 2, d = tid & 3;
    const float* pr = ps + rw * SP + d;
    const float* qr = pv + rw * SP + d;
    float s1 = pr[0]; int g1 = 0;
#pragma unroll
    for (int g = 1; g < 25; ++g) {
      float s = pr[g * 4];
      if (s > s1) { s1 = s; g1 = g; }
    }
    unsigned char viol = 0;
    float p1 = qr[g1 * 4];
    if (p1 <= 2.f * CERT_E) {
      viol = 1;
    } else {
      float thr = s1 + logf(1.f - CERT_E / p1);
#pragma unroll
      for (int g = 0; g < 25; ++g) {
        if (g != g1) {
          float shi = pr[g * 4] + logf(1.f + CERT_E / qr[g * 4]);
          if (shi >= thr) viol = 1;
        }
      }
    }
    idxsh[tid] = g1;
    fsite[tid] = viol;
  }
  __syncthreads();

  if (tid < 32) {
    if (fsite[tid * 4] | fsite[tid * 4 + 1] | fsite[tid * 4 + 2] | fsite[tid * 4 + 3]) {
      int p = atomicAdd(&nflag, 1);
      flagrows[p] = tid;
    }
  }

  if (tid < 256) {
    int head = __builtin_amdgcn_readfirstlane(tid >> 7);
    int rem  = tid & 127;
    int rw   = rem >> 2, d = rem & 3;
    int g    = idxsh[rem];
    const float* Wh = head ? Wsg : Wmu;
    const float* bb = head ? bsg : bmu;
    int n = g * 4 + d;
    const float* hr = h3 + rw * SA3;
    const float* wp = Wh + (size_t)n * 200;
    float a = bb[n];
#pragma unroll 2
    for (int k0 = 0; k0 < 200; k0 += 4) {
      float4 h4 = *(const float4*)(hr + k0);
      float4 w4 = *(const float4*)(wp + k0);
      a = fmaf(h4.x, w4.x, a);
      a = fmaf(h4.y, w4.y, a);
      a = fmaf(h4.z, w4.z, a);
      a = fmaf(h4.w, w4.w, a);
    }
    if (head) sigsh[rem] = fabsf(a);
    else      mush [rem] = a;
  }
  __syncthreads();

  if (tid < 128) {
    int rw = tid >> 2, d = tid & 3;
    unsigned char rowflag = fsite[rw * 4] | fsite[rw * 4 + 1] |
                            fsite[rw * 4 + 2] | fsite[rw * 4 + 3];
    if (!rowflag) {
      float rv = rnd[(size_t)(r0 + rw) * 4 + d];
      out[(size_t)(r0 + rw) * 4 + d] = fmaf(rv, sigsh[tid], mush[tid]);
    }
  }
  __syncthreads();

  {
    double* rh1 = (double*)lds;
    double* rh2 = rh1 + 128;
    double* rh3 = rh2 + 256;
    double* rsc = rh3 + 200;
    double* rmu = rsc + 100;
    double* rsg = rmu + 4;
    const int nf = nflag;
    for (int i = 0; i < nf; ++i) {
      const int row = r0 + flagrows[i];

      if (tid < 128) {
        double a = (double)b1[tid];
        a = fma((double)x0[(size_t)row * 3 + 0], (double)W1[tid * 3 + 0], a);
        a = fma((double)x0[(size_t)row * 3 + 1], (double)W1[tid * 3 + 1], a);
        a = fma((double)x0[(size_t)row * 3 + 2], (double)W1[tid * 3 + 2], a);
        rh1[tid] = fmax(a, 0.0);
      }
      __syncthreads();

      if (tid < 256) {
        double a = (double)b2[tid];
        const float* wq = W2 + (size_t)tid * 128;
        for (int k = 0; k < 128; k += 4) {
          float4 w4 = *(const float4*)(wq + k);
          a = fma(rh1[k],     (double)w4.x, a);
          a = fma(rh1[k + 1], (double)w4.y, a);
          a = fma(rh1[k + 2], (double)w4.z, a);
          a = fma(rh1[k + 3], (double)w4.w, a);
        }
        rh2[tid] = fmax(a, 0.0);
      }
      __syncthreads();

      if (tid < 200) {
        double a = (double)b3[tid];
        const float* wq = W3 + (size_t)tid * 256;
        for (int k = 0; k < 256; k += 4) {
          float4 w4 = *(const float4*)(wq + k);
          a = fma(rh2[k],     (double)w4.x, a);
          a = fma(rh2[k + 1], (double)w4.y, a);
          a = fma(rh2[k + 2], (double)w4.z, a);
          a = fma(rh2[k + 3], (double)w4.w, a);
        }
        rh3[tid] = fmax(a, 0.0);
      }
      __syncthreads();

      if (tid < 100) {
        double a = (double)bpi[tid];
        const float* wq = Wpi + (size_t)tid * 200;
        for (int k = 0; k < 200; k += 4) {
          float4 w4 = *(const float4*)(wq + k);
          a = fma(rh3[k],     (double)w4.x, a);
          a = fma(rh3[k + 1], (double)w4.y, a);
          a = fma(rh3[k + 2], (double)w4.z, a);
          a = fma(rh3[k + 3], (double)w4.w, a);
        }
        rsc[tid] = log(fabs(a) + 1e-12) + (double)gmb[(size_t)row * 100 + tid];
      }
      __syncthreads();

      if (tid < 4) {
        double best = rsc[tid]; int bi = 0;
        for (int g = 1; g < 25; ++g) {
          double s = rsc[g * 4 + tid];
          if (s > best) { best = s; bi = g; }
        }
        ridx[tid] = bi;
      }
      __syncthreads();

      if (tid < 8) {
        int head = tid >> 2, d = tid & 3;
        int n = ridx[d] * 4 + d;
        const float* Wh = head ? Wsg : Wmu;
        const float* bb = head ? bsg : bmu;
        double a = (double)bb[n];
        const float* wq = Wh + (size_t)n * 200;
        for (int k = 0; k < 200; k += 4) {
          float4 w4 = *(const float4*)(wq + k);
          a = fma(rh3[k],     (double)w4.x, a);
          a = fma(rh3[k + 1], (double)w4.y, a);
          a = fma(rh3[k + 2], (double)w4.z, a);
          a = fma(rh3[k + 3], (double)w4.w, a);
        }
        if (head) rsg[d] = fabs(a);
        else      rmu[d] = a;
      }
      __syncthreads();

      if (tid < 4) {
        double rv = (double)rnd[(size_t)row * 4 + tid];
        out[(size_t)row * 4 + tid] = (float)fma(rv, rsg[tid], rmu[tid]);
      }
      __syncthreads();
    }
  }
}

// ============================================================================
extern "C" void kernel_launch(void* const* d_in, const int* in_sizes, int n_in,
                              void* d_out, int out_size, void* d_ws, size_t ws_size,
                              hipStream_t stream) {
  (void)out_size;
  float* out = (float*)d_out;

  static const int want[15] = {786432, 1048576, 26214400, 384, 128, 32768, 256,
                               51200, 200, 20000, 100, 20000, 100, 20000, 100};
  const float* p[15];
  bool used[64] = {false};
  bool ok = (n_in == 15);
  if (ok) {
    for (int j = 0; j < 15; ++j) {
      int found = -1;
      for (int i = 0; i < n_in; ++i)
        if (!used[i] && in_sizes[i] == want[j]) { found = i; break; }
      if (found < 0) { ok = false; break; }
      used[found] = true;
      p[j] = (const float*)d_in[found];
    }
  }
  if (!ok) return;

  if (d_ws && ws_size >= (size_t)WS_NEED) {
    mdn_prep<<<256, 256, 0, stream>>>(p[5], p[7], (unsigned char*)d_ws);
    fused_mdn_mfma<<<262144 / NROWS, 512, 0, stream>>>(
        p[0], p[1], p[2], p[3], p[4], p[5], p[6], p[7], p[8],
        p[9], p[10], p[11], p[12], p[13], p[14],
        (const unsigned char*)d_ws, out);
  } else {
    fused_mdn_f32<<<262144 / 32, 512, 0, stream>>>(
        p[0], p[1], p[2], p[3], p[4], p[5], p[6], p[7], p[8],
        p[9], p[10], p[11], p[12], p[13], p[14], out);
  }
}